// Round 5
// baseline (1660.248 us; speedup 1.0000x reference)
//
#include <hip/hip_runtime.h>
#include <math.h>

// Problem constants (fixed by setup_inputs)
#define NS   2
#define NVIN 3
#define NVT  4
#define NC   16
#define ND   64
#define NH   96
#define NW   96
#define HWH  48          // half res h=w
#define SPR  64
#define DHW  (ND*NH*NW)  // 589824
#define NTILE (DHW / 64) // 9216 tiles per (s,v) volume — NOT a power of two!

// ---------------------------------------------------------------------------
// LDS-tiled transpose enc [6][16][DHW] -> enc_t [6][DHW][16].
// ---------------------------------------------------------------------------
__global__ __launch_bounds__(256) void transpose_kernel(
    const float* __restrict__ in, float* __restrict__ out)
{
    __shared__ float tile[NC][64 + 4];
    const int t   = threadIdx.x;
    const int blk = blockIdx.x;               // 6*NTILE blocks
    const int vox0 = (blk % NTILE) * 64;
    const int sv   = blk / NTILE;

    const int c    = t >> 4;
    const int vg   = (t & 15) * 4;
    const float* src = in + ((size_t)sv * NC + c) * DHW + vox0 + vg;
    float4 v = *(const float4*)src;
    tile[c][vg + 0] = v.x; tile[c][vg + 1] = v.y;
    tile[c][vg + 2] = v.z; tile[c][vg + 3] = v.w;
    __syncthreads();

    const int ov = t >> 2;        // 0..63 voxel within tile
    const int oc = (t & 3) * 4;   // channel group
    float4 w = make_float4(tile[oc + 0][ov], tile[oc + 1][ov],
                           tile[oc + 2][ov], tile[oc + 3][ov]);
    float* dst = out + ((size_t)sv * DHW + vox0 + ov) * NC + oc;
    *(float4*)dst = w;
}

// ---------------------------------------------------------------------------
// Fused render, channel-last gather. One wave per ray, lane = depth sample.
// CRITICAL: every private-array access must have a COMPILE-TIME index, or the
// array is demoted to scratch (R2/R4: `#pragma unroll 4` left runtime k in
// h2a[k] -> 564 MB of scratch traffic, 2.4 TB/s HBM, 458 us). Full unroll.
// ---------------------------------------------------------------------------
__global__ __launch_bounds__(256) void render_cl_kernel(
    const float* __restrict__ enc_t,
    const float* __restrict__ ipose,
    const float* __restrict__ tpose,
    const float* __restrict__ focal_p,
    const float* __restrict__ znear_p,
    const float* __restrict__ zfar_p,
    const float* __restrict__ W1, const float* __restrict__ B1,
    const float* __restrict__ W2, const float* __restrict__ B2,
    const float* __restrict__ W3, const float* __restrict__ B3,
    float* __restrict__ rhalf)
{
    const int lane = threadIdx.x & 63;
    const int ray  = blockIdx.x * 4 + (threadIdx.x >> 6);
    const int px   = ray % HWH;
    const int py   = (ray / HWH) % HWH;
    const int b    = ray / (HWH * HWH);   // s*NVT + t
    const int s    = b >> 2;

    const float focal = focal_p[0];
    const float znear = znear_p[0];
    const float zfar  = zfar_p[0];

    // ---- ray generation ----
    const float* P = tpose + b * 16;
    float ysc = ((py + 0.5f) / (float)HWH) * 2.f - 1.f;
    float xsc = ((px + 0.5f) / (float)HWH) * 2.f - 1.f;
    float dcx = xsc / focal, dcy = -ysc / focal, dcz = -1.f;
    float dirx = P[0]*dcx + P[1]*dcy + P[2]*dcz;
    float diry = P[4]*dcx + P[5]*dcy + P[6]*dcz;
    float dirz = P[8]*dcx + P[9]*dcy + P[10]*dcz;
    float ox = P[3], oy = P[7], oz = P[11];

    float tv  = znear + (zfar - znear) * ((float)lane / (float)(SPR - 1));
    float ptx = ox + tv * dirx, pty = oy + tv * diry, ptz = oz + tv * dirz;

    float feats[NC];
    #pragma unroll
    for (int c = 0; c < NC; c++) feats[c] = 0.f;

    const float minz = focal * znear, maxz = focal * zfar;

    // ---- 3-view trilinear gather (channel-last: 64B per corner) ----
    for (int v = 0; v < NVIN; v++) {
        const float* E = ipose + (s * NVIN + v) * 16;
        float qx = ptx - E[3], qy = pty - E[7], qz = ptz - E[11];
        float lx = E[0]*qx + E[4]*qy + E[8]*qz;
        float ly = E[1]*qx + E[5]*qy + E[9]*qz;
        float lz = E[2]*qx + E[6]*qy + E[10]*qz;
        float zz = -lz;
        float u  = lx / zz * focal;
        float vv = ly / zz * focal;
        float wd = 2.f * (zz - minz) / (maxz - minz) - 1.f;
        float ix = ((u   + 1.f) * NW - 1.f) * 0.5f;
        float iy = ((-vv + 1.f) * NH - 1.f) * 0.5f;
        float iz = ((-wd + 1.f) * ND - 1.f) * 0.5f;
        float x0 = floorf(ix), y0 = floorf(iy), z0 = floorf(iz);

        float wgt[8]; int idx[8];
        #pragma unroll
        for (int k = 0; k < 8; k++) {
            float xc = x0 + (k & 1), yc = y0 + ((k >> 1) & 1), zc = z0 + (k >> 2);
            float wt = (1.f - fabsf(ix - xc)) * (1.f - fabsf(iy - yc)) * (1.f - fabsf(iz - zc));
            bool valid = (xc >= 0.f) && (xc < (float)NW) &&
                         (yc >= 0.f) && (yc < (float)NH) &&
                         (zc >= 0.f) && (zc < (float)ND);
            wgt[k] = valid ? wt : 0.f;
            int xi = min(max((int)xc, 0), NW - 1);
            int yi = min(max((int)yc, 0), NH - 1);
            int zi = min(max((int)zc, 0), ND - 1);
            idx[k] = (zi * NH + yi) * NW + xi;
        }
        const float* VB = enc_t + (size_t)(s * NVIN + v) * DHW * NC;
        #pragma unroll
        for (int k = 0; k < 8; k++) {
            const float* p = VB + (size_t)idx[k] * NC;
            float4 a0 = *(const float4*)(p);
            float4 a1 = *(const float4*)(p + 4);
            float4 a2 = *(const float4*)(p + 8);
            float4 a3 = *(const float4*)(p + 12);
            float w = wgt[k];
            feats[0]  += w * a0.x; feats[1]  += w * a0.y;
            feats[2]  += w * a0.z; feats[3]  += w * a0.w;
            feats[4]  += w * a1.x; feats[5]  += w * a1.y;
            feats[6]  += w * a1.z; feats[7]  += w * a1.w;
            feats[8]  += w * a2.x; feats[9]  += w * a2.y;
            feats[10] += w * a2.z; feats[11] += w * a2.w;
            feats[12] += w * a3.x; feats[13] += w * a3.y;
            feats[14] += w * a3.z; feats[15] += w * a3.w;
        }
    }
    #pragma unroll
    for (int c = 0; c < NC; c++) feats[c] *= (1.f / 3.f);

    // ---- fused MLP, FULLY unrolled (all array indices compile-time) ----
    float h2a[64];
    #pragma unroll
    for (int k = 0; k < 64; k++) h2a[k] = B2[k];
    #pragma unroll
    for (int j = 0; j < 64; j++) {
        float a = B1[j];
        #pragma unroll
        for (int i = 0; i < NC; i++) a += feats[i] * W1[i * 64 + j];
        a = fmaxf(a, 0.f);
        #pragma unroll
        for (int k = 0; k < 64; k++) h2a[k] += a * W2[j * 64 + k];
    }
    float outa[17];
    #pragma unroll
    for (int c = 0; c < 17; c++) outa[c] = B3[c];
    #pragma unroll
    for (int k = 0; k < 64; k++) {
        float hv = fmaxf(h2a[k], 0.f);
        #pragma unroll
        for (int c = 0; c < 17; c++) outa[c] += hv * W3[k * 17 + c];
    }
    float density = fmaxf(outa[0], 0.f);

    // ---- per-ray compositing ----
    float tn = znear + (zfar - znear) * ((float)(lane + 1) / (float)(SPR - 1));
    float delta = (lane < SPR - 1) ? (tn - tv) : 1e10f;
    float sigdel = density * delta;
    float alpha = 1.f - expf(-sigdel);
    float csum = sigdel;
    #pragma unroll
    for (int off = 1; off < 64; off <<= 1) {
        float nb = __shfl_up(csum, off, 64);
        if (lane >= off) csum += nb;
    }
    float wray = alpha * expf(-csum);

    #pragma unroll
    for (int c = 0; c < NC; c++) {
        float val = wray * (feats[c] + outa[1 + c]);
        #pragma unroll
        for (int off = 32; off >= 1; off >>= 1)
            val += __shfl_down(val, off, 64);
        if (lane == 0)
            rhalf[((b * NC + c) * HWH + py) * HWH + px] = val;
    }
}

// ---------------------------------------------------------------------------
// Fallback render (channel-first) — used only if ws too small.
// ---------------------------------------------------------------------------
__global__ __launch_bounds__(256) void render_kernel(
    const float* __restrict__ enc,
    const float* __restrict__ ipose,
    const float* __restrict__ tpose,
    const float* __restrict__ focal_p,
    const float* __restrict__ znear_p,
    const float* __restrict__ zfar_p,
    const float* __restrict__ W1, const float* __restrict__ B1,
    const float* __restrict__ W2, const float* __restrict__ B2,
    const float* __restrict__ W3, const float* __restrict__ B3,
    float* __restrict__ rhalf)
{
    const int lane = threadIdx.x & 63;
    const int ray  = blockIdx.x * 4 + (threadIdx.x >> 6);
    const int px   = ray % HWH;
    const int py   = (ray / HWH) % HWH;
    const int b    = ray / (HWH * HWH);
    const int s    = b >> 2;

    const float focal = focal_p[0];
    const float znear = znear_p[0];
    const float zfar  = zfar_p[0];

    const float* P = tpose + b * 16;
    float ysc = ((py + 0.5f) / (float)HWH) * 2.f - 1.f;
    float xsc = ((px + 0.5f) / (float)HWH) * 2.f - 1.f;
    float dcx = xsc / focal, dcy = -ysc / focal, dcz = -1.f;
    float dirx = P[0]*dcx + P[1]*dcy + P[2]*dcz;
    float diry = P[4]*dcx + P[5]*dcy + P[6]*dcz;
    float dirz = P[8]*dcx + P[9]*dcy + P[10]*dcz;
    float ox = P[3], oy = P[7], oz = P[11];

    float tv  = znear + (zfar - znear) * ((float)lane / (float)(SPR - 1));
    float ptx = ox + tv * dirx, pty = oy + tv * diry, ptz = oz + tv * dirz;

    float feats[NC];
    #pragma unroll
    for (int c = 0; c < NC; c++) feats[c] = 0.f;

    const float minz = focal * znear, maxz = focal * zfar;

    for (int v = 0; v < NVIN; v++) {
        const float* E = ipose + (s * NVIN + v) * 16;
        float qx = ptx - E[3], qy = pty - E[7], qz = ptz - E[11];
        float lx = E[0]*qx + E[4]*qy + E[8]*qz;
        float ly = E[1]*qx + E[5]*qy + E[9]*qz;
        float lz = E[2]*qx + E[6]*qy + E[10]*qz;
        float zz = -lz;
        float u  = lx / zz * focal;
        float vv = ly / zz * focal;
        float wd = 2.f * (zz - minz) / (maxz - minz) - 1.f;
        float ix = ((u   + 1.f) * NW - 1.f) * 0.5f;
        float iy = ((-vv + 1.f) * NH - 1.f) * 0.5f;
        float iz = ((-wd + 1.f) * ND - 1.f) * 0.5f;
        float x0 = floorf(ix), y0 = floorf(iy), z0 = floorf(iz);

        float wgt[8]; int idx[8];
        #pragma unroll
        for (int k = 0; k < 8; k++) {
            float xc = x0 + (k & 1), yc = y0 + ((k >> 1) & 1), zc = z0 + (k >> 2);
            float wt = (1.f - fabsf(ix - xc)) * (1.f - fabsf(iy - yc)) * (1.f - fabsf(iz - zc));
            bool valid = (xc >= 0.f) && (xc < (float)NW) &&
                         (yc >= 0.f) && (yc < (float)NH) &&
                         (zc >= 0.f) && (zc < (float)ND);
            wgt[k] = valid ? wt : 0.f;
            int xi = min(max((int)xc, 0), NW - 1);
            int yi = min(max((int)yc, 0), NH - 1);
            int zi = min(max((int)zc, 0), ND - 1);
            idx[k] = (zi * NH + yi) * NW + xi;
        }
        const float* VB = enc + (size_t)(s * NVIN + v) * NC * DHW;
        #pragma unroll
        for (int c = 0; c < NC; c++) {
            const float* vc = VB + c * DHW;
            float acc = 0.f;
            #pragma unroll
            for (int k = 0; k < 8; k++) acc += wgt[k] * vc[idx[k]];
            feats[c] += acc;
        }
    }
    #pragma unroll
    for (int c = 0; c < NC; c++) feats[c] *= (1.f / 3.f);

    float h2a[64];
    #pragma unroll
    for (int k = 0; k < 64; k++) h2a[k] = B2[k];
    #pragma unroll
    for (int j = 0; j < 64; j++) {
        float a = B1[j];
        #pragma unroll
        for (int i = 0; i < NC; i++) a += feats[i] * W1[i * 64 + j];
        a = fmaxf(a, 0.f);
        #pragma unroll
        for (int k = 0; k < 64; k++) h2a[k] += a * W2[j * 64 + k];
    }
    float outa[17];
    #pragma unroll
    for (int c = 0; c < 17; c++) outa[c] = B3[c];
    #pragma unroll
    for (int k = 0; k < 64; k++) {
        float hv = fmaxf(h2a[k], 0.f);
        #pragma unroll
        for (int c = 0; c < 17; c++) outa[c] += hv * W3[k * 17 + c];
    }
    float density = fmaxf(outa[0], 0.f);

    float tn = znear + (zfar - znear) * ((float)(lane + 1) / (float)(SPR - 1));
    float delta = (lane < SPR - 1) ? (tn - tv) : 1e10f;
    float sigdel = density * delta;
    float alpha = 1.f - expf(-sigdel);
    float csum = sigdel;
    #pragma unroll
    for (int off = 1; off < 64; off <<= 1) {
        float nb = __shfl_up(csum, off, 64);
        if (lane >= off) csum += nb;
    }
    float wray = alpha * expf(-csum);

    #pragma unroll
    for (int c = 0; c < NC; c++) {
        float val = wray * (feats[c] + outa[1 + c]);
        #pragma unroll
        for (int off = 32; off >= 1; off >>= 1)
            val += __shfl_down(val, off, 64);
        if (lane == 0)
            rhalf[((b * NC + c) * HWH + py) * HWH + px] = val;
    }
}

// 2x bilinear upsample, align_corners=True.
__global__ __launch_bounds__(256) void upsample_kernel(
    const float* __restrict__ in, float* __restrict__ out)
{
    int tid = blockIdx.x * 256 + threadIdx.x;
    int ox = tid % NW;
    int oy = (tid / NW) % NH;
    int c  = (tid / (NW * NH)) % NC;
    int b  = tid / (NW * NH * NC);
    const float sc = (float)((HWH - 1) / (double)(NH - 1)); // 47/95
    float pyf = oy * sc;
    float pxf = ox * sc;
    int y0 = (int)floorf(pyf); int y1 = min(y0 + 1, HWH - 1); float fy = pyf - y0;
    int x0 = (int)floorf(pxf); int x1 = min(x0 + 1, HWH - 1); float fx = pxf - x0;
    const float* src = in + (b * NC + c) * HWH * HWH;
    float v00 = src[y0 * HWH + x0], v01 = src[y0 * HWH + x1];
    float v10 = src[y1 * HWH + x0], v11 = src[y1 * HWH + x1];
    float gl = v00 * (1.f - fy) + v10 * fy;
    float gr = v01 * (1.f - fy) + v11 * fy;
    out[tid] = gl * (1.f - fx) + gr * fx;
}

extern "C" void kernel_launch(void* const* d_in, const int* in_sizes, int n_in,
                              void* d_out, int out_size, void* d_ws, size_t ws_size,
                              hipStream_t stream) {
    const float* enc   = (const float*)d_in[0];
    const float* ipose = (const float*)d_in[1];
    const float* tpose = (const float*)d_in[2];
    const float* focal = (const float*)d_in[3];
    const float* znear = (const float*)d_in[4];
    const float* zfar  = (const float*)d_in[5];
    const float* W1 = (const float*)d_in[7];
    const float* B1 = (const float*)d_in[8];
    const float* W2 = (const float*)d_in[9];
    const float* B2 = (const float*)d_in[10];
    const float* W3 = (const float*)d_in[11];
    const float* B3 = (const float*)d_in[12];

    float* out = (float*)d_out;
    const int nrays = NS * NVT * HWH * HWH;              // 18432
    const int nout  = NS * NVT * NC * NH * NW;           // 1179648
    const size_t enc_t_bytes = (size_t)NS * NVIN * NC * DHW * 4;   // 226.5 MB
    const size_t rhalf_bytes = (size_t)NS * NVT * NC * HWH * HWH * 4;

    if (ws_size >= enc_t_bytes + rhalf_bytes) {
        float* enc_t = (float*)d_ws;
        float* rhalf = (float*)((char*)d_ws + enc_t_bytes);
        const int ntiles = NS * NVIN * NTILE;            // 55296 blocks
        transpose_kernel<<<ntiles, 256, 0, stream>>>(enc, enc_t);
        render_cl_kernel<<<nrays / 4, 256, 0, stream>>>(
            enc_t, ipose, tpose, focal, znear, zfar,
            W1, B1, W2, B2, W3, B3, rhalf);
        upsample_kernel<<<nout / 256, 256, 0, stream>>>(rhalf, out);
    } else {
        float* rhalf = (float*)d_ws;
        render_kernel<<<nrays / 4, 256, 0, stream>>>(
            enc, ipose, tpose, focal, znear, zfar,
            W1, B1, W2, B2, W3, B3, rhalf);
        upsample_kernel<<<nout / 256, 256, 0, stream>>>(rhalf, out);
    }
}

// Round 6
// 796.610 us; speedup vs baseline: 2.0841x; 2.0841x over previous
//
#include <hip/hip_runtime.h>
#include <math.h>

// Problem constants (fixed by setup_inputs)
#define NS   2
#define NVIN 3
#define NVT  4
#define NC   16
#define ND   64
#define NH   96
#define NW   96
#define HWH  48          // half res h=w
#define SPR  64
#define DHW  (ND*NH*NW)  // 589824
#define NTILE (DHW / 64) // 9216 tiles per (s,v) volume — NOT a power of two!

// ---------------------------------------------------------------------------
// LDS-tiled transpose enc [6][16][DHW] -> enc_t [6][DHW][16].
// ---------------------------------------------------------------------------
__global__ __launch_bounds__(256) void transpose_kernel(
    const float* __restrict__ in, float* __restrict__ out)
{
    __shared__ float tile[NC][64 + 4];
    const int t   = threadIdx.x;
    const int blk = blockIdx.x;               // 6*NTILE blocks
    const int vox0 = (blk % NTILE) * 64;
    const int sv   = blk / NTILE;

    const int c    = t >> 4;
    const int vg   = (t & 15) * 4;
    const float* src = in + ((size_t)sv * NC + c) * DHW + vox0 + vg;
    float4 v = *(const float4*)src;
    tile[c][vg + 0] = v.x; tile[c][vg + 1] = v.y;
    tile[c][vg + 2] = v.z; tile[c][vg + 3] = v.w;
    __syncthreads();

    const int ov = t >> 2;        // 0..63 voxel within tile
    const int oc = (t & 3) * 4;   // channel group
    float4 w = make_float4(tile[oc + 0][ov], tile[oc + 1][ov],
                           tile[oc + 2][ov], tile[oc + 3][ov]);
    float* dst = out + ((size_t)sv * DHW + vox0 + ov) * NC + oc;
    *(float4*)dst = w;
}

// ---------------------------------------------------------------------------
// Chunked MLP: h2 in 4 chunks of 16 accumulators, h1 recomputed per chunk,
// chunk folded into outa[17] immediately. Live set ~feats[16]+h2c[16]+outa[17]
// ≈ 50-60 floats — small enough that the allocator keeps it in real VGPRs.
// History: 64-float h2a[64] per thread caused scratch spill at low VGPR cap
// (R2/R4: 564 MB scratch traffic) or AGPR-shuttle bloat when fully unrolled
// (R5: VALUBusy 84%, 11x instruction bloat). Rule: private-array indices must
// be compile-time constants; runtime j/kc in GLOBAL weight offsets is fine.
// ---------------------------------------------------------------------------
__device__ __forceinline__ void mlp_and_composite(
    const float feats[NC], int lane, int b, int py, int px,
    float tv, float znear, float zfar,
    const float* __restrict__ W1, const float* __restrict__ B1,
    const float* __restrict__ W2, const float* __restrict__ B2,
    const float* __restrict__ W3, const float* __restrict__ B3,
    float* __restrict__ rhalf)
{
    float outa[17];
    #pragma unroll
    for (int c = 0; c < 17; c++) outa[c] = B3[c];

    for (int kc = 0; kc < 4; kc++) {          // h2-channel chunk (runtime ok)
        float h2c[16];
        #pragma unroll
        for (int k = 0; k < 16; k++) h2c[k] = B2[kc * 16 + k];
        #pragma unroll 4
        for (int j = 0; j < 64; j++) {        // runtime j: global offsets only
            float a = B1[j];
            #pragma unroll
            for (int i = 0; i < NC; i++) a += feats[i] * W1[i * 64 + j];
            a = fmaxf(a, 0.f);
            const float* w2p = W2 + j * 64 + kc * 16;
            #pragma unroll
            for (int k = 0; k < 16; k++) h2c[k] += a * w2p[k];
        }
        #pragma unroll
        for (int k = 0; k < 16; k++) {
            float hv = fmaxf(h2c[k], 0.f);
            const float* w3p = W3 + (kc * 16 + k) * 17;
            #pragma unroll
            for (int c = 0; c < 17; c++) outa[c] += hv * w3p[c];
        }
    }
    float density = fmaxf(outa[0], 0.f);

    // ---- per-ray compositing (wave = ray, lane = sample) ----
    float tn = znear + (zfar - znear) * ((float)(lane + 1) / (float)(SPR - 1));
    float delta = (lane < SPR - 1) ? (tn - tv) : 1e10f;
    float sigdel = density * delta;
    float alpha = 1.f - expf(-sigdel);
    float csum = sigdel;
    #pragma unroll
    for (int off = 1; off < 64; off <<= 1) {
        float nb = __shfl_up(csum, off, 64);
        if (lane >= off) csum += nb;
    }
    float wray = alpha * expf(-csum);

    #pragma unroll
    for (int c = 0; c < NC; c++) {
        float val = wray * (feats[c] + outa[1 + c]);
        #pragma unroll
        for (int off = 32; off >= 1; off >>= 1)
            val += __shfl_down(val, off, 64);
        if (lane == 0)
            rhalf[((b * NC + c) * HWH + py) * HWH + px] = val;
    }
}

// ---------------------------------------------------------------------------
// Fused render, channel-last gather. One wave per ray, lane = depth sample.
// ---------------------------------------------------------------------------
__global__ __launch_bounds__(256) void render_cl_kernel(
    const float* __restrict__ enc_t,
    const float* __restrict__ ipose,
    const float* __restrict__ tpose,
    const float* __restrict__ focal_p,
    const float* __restrict__ znear_p,
    const float* __restrict__ zfar_p,
    const float* __restrict__ W1, const float* __restrict__ B1,
    const float* __restrict__ W2, const float* __restrict__ B2,
    const float* __restrict__ W3, const float* __restrict__ B3,
    float* __restrict__ rhalf)
{
    const int lane = threadIdx.x & 63;
    const int ray  = blockIdx.x * 4 + (threadIdx.x >> 6);
    const int px   = ray % HWH;
    const int py   = (ray / HWH) % HWH;
    const int b    = ray / (HWH * HWH);   // s*NVT + t
    const int s    = b >> 2;

    const float focal = focal_p[0];
    const float znear = znear_p[0];
    const float zfar  = zfar_p[0];

    // ---- ray generation ----
    const float* P = tpose + b * 16;
    float ysc = ((py + 0.5f) / (float)HWH) * 2.f - 1.f;
    float xsc = ((px + 0.5f) / (float)HWH) * 2.f - 1.f;
    float dcx = xsc / focal, dcy = -ysc / focal, dcz = -1.f;
    float dirx = P[0]*dcx + P[1]*dcy + P[2]*dcz;
    float diry = P[4]*dcx + P[5]*dcy + P[6]*dcz;
    float dirz = P[8]*dcx + P[9]*dcy + P[10]*dcz;
    float ox = P[3], oy = P[7], oz = P[11];

    float tv  = znear + (zfar - znear) * ((float)lane / (float)(SPR - 1));
    float ptx = ox + tv * dirx, pty = oy + tv * diry, ptz = oz + tv * dirz;

    float feats[NC];
    #pragma unroll
    for (int c = 0; c < NC; c++) feats[c] = 0.f;

    const float minz = focal * znear, maxz = focal * zfar;

    // ---- 3-view trilinear gather (channel-last: 64B per corner) ----
    for (int v = 0; v < NVIN; v++) {
        const float* E = ipose + (s * NVIN + v) * 16;
        float qx = ptx - E[3], qy = pty - E[7], qz = ptz - E[11];
        float lx = E[0]*qx + E[4]*qy + E[8]*qz;
        float ly = E[1]*qx + E[5]*qy + E[9]*qz;
        float lz = E[2]*qx + E[6]*qy + E[10]*qz;
        float zz = -lz;
        float u  = lx / zz * focal;
        float vv = ly / zz * focal;
        float wd = 2.f * (zz - minz) / (maxz - minz) - 1.f;
        float ix = ((u   + 1.f) * NW - 1.f) * 0.5f;
        float iy = ((-vv + 1.f) * NH - 1.f) * 0.5f;
        float iz = ((-wd + 1.f) * ND - 1.f) * 0.5f;
        float x0 = floorf(ix), y0 = floorf(iy), z0 = floorf(iz);

        float wgt[8]; int idx[8];
        #pragma unroll
        for (int k = 0; k < 8; k++) {
            float xc = x0 + (k & 1), yc = y0 + ((k >> 1) & 1), zc = z0 + (k >> 2);
            float wt = (1.f - fabsf(ix - xc)) * (1.f - fabsf(iy - yc)) * (1.f - fabsf(iz - zc));
            bool valid = (xc >= 0.f) && (xc < (float)NW) &&
                         (yc >= 0.f) && (yc < (float)NH) &&
                         (zc >= 0.f) && (zc < (float)ND);
            wgt[k] = valid ? wt : 0.f;
            int xi = min(max((int)xc, 0), NW - 1);
            int yi = min(max((int)yc, 0), NH - 1);
            int zi = min(max((int)zc, 0), ND - 1);
            idx[k] = (zi * NH + yi) * NW + xi;
        }
        const float* VB = enc_t + (size_t)(s * NVIN + v) * DHW * NC;
        #pragma unroll
        for (int k = 0; k < 8; k++) {
            const float* p = VB + (size_t)idx[k] * NC;
            float4 a0 = *(const float4*)(p);
            float4 a1 = *(const float4*)(p + 4);
            float4 a2 = *(const float4*)(p + 8);
            float4 a3 = *(const float4*)(p + 12);
            float w = wgt[k];
            feats[0]  += w * a0.x; feats[1]  += w * a0.y;
            feats[2]  += w * a0.z; feats[3]  += w * a0.w;
            feats[4]  += w * a1.x; feats[5]  += w * a1.y;
            feats[6]  += w * a1.z; feats[7]  += w * a1.w;
            feats[8]  += w * a2.x; feats[9]  += w * a2.y;
            feats[10] += w * a2.z; feats[11] += w * a2.w;
            feats[12] += w * a3.x; feats[13] += w * a3.y;
            feats[14] += w * a3.z; feats[15] += w * a3.w;
        }
    }
    #pragma unroll
    for (int c = 0; c < NC; c++) feats[c] *= (1.f / 3.f);

    mlp_and_composite(feats, lane, b, py, px, tv, znear, zfar,
                      W1, B1, W2, B2, W3, B3, rhalf);
}

// ---------------------------------------------------------------------------
// Fallback render (channel-first) — used only if ws too small.
// ---------------------------------------------------------------------------
__global__ __launch_bounds__(256) void render_kernel(
    const float* __restrict__ enc,
    const float* __restrict__ ipose,
    const float* __restrict__ tpose,
    const float* __restrict__ focal_p,
    const float* __restrict__ znear_p,
    const float* __restrict__ zfar_p,
    const float* __restrict__ W1, const float* __restrict__ B1,
    const float* __restrict__ W2, const float* __restrict__ B2,
    const float* __restrict__ W3, const float* __restrict__ B3,
    float* __restrict__ rhalf)
{
    const int lane = threadIdx.x & 63;
    const int ray  = blockIdx.x * 4 + (threadIdx.x >> 6);
    const int px   = ray % HWH;
    const int py   = (ray / HWH) % HWH;
    const int b    = ray / (HWH * HWH);
    const int s    = b >> 2;

    const float focal = focal_p[0];
    const float znear = znear_p[0];
    const float zfar  = zfar_p[0];

    const float* P = tpose + b * 16;
    float ysc = ((py + 0.5f) / (float)HWH) * 2.f - 1.f;
    float xsc = ((px + 0.5f) / (float)HWH) * 2.f - 1.f;
    float dcx = xsc / focal, dcy = -ysc / focal, dcz = -1.f;
    float dirx = P[0]*dcx + P[1]*dcy + P[2]*dcz;
    float diry = P[4]*dcx + P[5]*dcy + P[6]*dcz;
    float dirz = P[8]*dcx + P[9]*dcy + P[10]*dcz;
    float ox = P[3], oy = P[7], oz = P[11];

    float tv  = znear + (zfar - znear) * ((float)lane / (float)(SPR - 1));
    float ptx = ox + tv * dirx, pty = oy + tv * diry, ptz = oz + tv * dirz;

    float feats[NC];
    #pragma unroll
    for (int c = 0; c < NC; c++) feats[c] = 0.f;

    const float minz = focal * znear, maxz = focal * zfar;

    for (int v = 0; v < NVIN; v++) {
        const float* E = ipose + (s * NVIN + v) * 16;
        float qx = ptx - E[3], qy = pty - E[7], qz = ptz - E[11];
        float lx = E[0]*qx + E[4]*qy + E[8]*qz;
        float ly = E[1]*qx + E[5]*qy + E[9]*qz;
        float lz = E[2]*qx + E[6]*qy + E[10]*qz;
        float zz = -lz;
        float u  = lx / zz * focal;
        float vv = ly / zz * focal;
        float wd = 2.f * (zz - minz) / (maxz - minz) - 1.f;
        float ix = ((u   + 1.f) * NW - 1.f) * 0.5f;
        float iy = ((-vv + 1.f) * NH - 1.f) * 0.5f;
        float iz = ((-wd + 1.f) * ND - 1.f) * 0.5f;
        float x0 = floorf(ix), y0 = floorf(iy), z0 = floorf(iz);

        float wgt[8]; int idx[8];
        #pragma unroll
        for (int k = 0; k < 8; k++) {
            float xc = x0 + (k & 1), yc = y0 + ((k >> 1) & 1), zc = z0 + (k >> 2);
            float wt = (1.f - fabsf(ix - xc)) * (1.f - fabsf(iy - yc)) * (1.f - fabsf(iz - zc));
            bool valid = (xc >= 0.f) && (xc < (float)NW) &&
                         (yc >= 0.f) && (yc < (float)NH) &&
                         (zc >= 0.f) && (zc < (float)ND);
            wgt[k] = valid ? wt : 0.f;
            int xi = min(max((int)xc, 0), NW - 1);
            int yi = min(max((int)yc, 0), NH - 1);
            int zi = min(max((int)zc, 0), ND - 1);
            idx[k] = (zi * NH + yi) * NW + xi;
        }
        const float* VB = enc + (size_t)(s * NVIN + v) * NC * DHW;
        #pragma unroll
        for (int c = 0; c < NC; c++) {
            const float* vc = VB + c * DHW;
            float acc = 0.f;
            #pragma unroll
            for (int k = 0; k < 8; k++) acc += wgt[k] * vc[idx[k]];
            feats[c] += acc;
        }
    }
    #pragma unroll
    for (int c = 0; c < NC; c++) feats[c] *= (1.f / 3.f);

    mlp_and_composite(feats, lane, b, py, px, tv, znear, zfar,
                      W1, B1, W2, B2, W3, B3, rhalf);
}

// 2x bilinear upsample, align_corners=True.
__global__ __launch_bounds__(256) void upsample_kernel(
    const float* __restrict__ in, float* __restrict__ out)
{
    int tid = blockIdx.x * 256 + threadIdx.x;
    int ox = tid % NW;
    int oy = (tid / NW) % NH;
    int c  = (tid / (NW * NH)) % NC;
    int b  = tid / (NW * NH * NC);
    const float sc = (float)((HWH - 1) / (double)(NH - 1)); // 47/95
    float pyf = oy * sc;
    float pxf = ox * sc;
    int y0 = (int)floorf(pyf); int y1 = min(y0 + 1, HWH - 1); float fy = pyf - y0;
    int x0 = (int)floorf(pxf); int x1 = min(x0 + 1, HWH - 1); float fx = pxf - x0;
    const float* src = in + (b * NC + c) * HWH * HWH;
    float v00 = src[y0 * HWH + x0], v01 = src[y0 * HWH + x1];
    float v10 = src[y1 * HWH + x0], v11 = src[y1 * HWH + x1];
    float gl = v00 * (1.f - fy) + v10 * fy;
    float gr = v01 * (1.f - fy) + v11 * fy;
    out[tid] = gl * (1.f - fx) + gr * fx;
}

extern "C" void kernel_launch(void* const* d_in, const int* in_sizes, int n_in,
                              void* d_out, int out_size, void* d_ws, size_t ws_size,
                              hipStream_t stream) {
    const float* enc   = (const float*)d_in[0];
    const float* ipose = (const float*)d_in[1];
    const float* tpose = (const float*)d_in[2];
    const float* focal = (const float*)d_in[3];
    const float* znear = (const float*)d_in[4];
    const float* zfar  = (const float*)d_in[5];
    const float* W1 = (const float*)d_in[7];
    const float* B1 = (const float*)d_in[8];
    const float* W2 = (const float*)d_in[9];
    const float* B2 = (const float*)d_in[10];
    const float* W3 = (const float*)d_in[11];
    const float* B3 = (const float*)d_in[12];

    float* out = (float*)d_out;
    const int nrays = NS * NVT * HWH * HWH;              // 18432
    const int nout  = NS * NVT * NC * NH * NW;           // 1179648
    const size_t enc_t_bytes = (size_t)NS * NVIN * NC * DHW * 4;   // 226.5 MB
    const size_t rhalf_bytes = (size_t)NS * NVT * NC * HWH * HWH * 4;

    if (ws_size >= enc_t_bytes + rhalf_bytes) {
        float* enc_t = (float*)d_ws;
        float* rhalf = (float*)((char*)d_ws + enc_t_bytes);
        const int ntiles = NS * NVIN * NTILE;            // 55296 blocks
        transpose_kernel<<<ntiles, 256, 0, stream>>>(enc, enc_t);
        render_cl_kernel<<<nrays / 4, 256, 0, stream>>>(
            enc_t, ipose, tpose, focal, znear, zfar,
            W1, B1, W2, B2, W3, B3, rhalf);
        upsample_kernel<<<nout / 256, 256, 0, stream>>>(rhalf, out);
    } else {
        float* rhalf = (float*)d_ws;
        render_kernel<<<nrays / 4, 256, 0, stream>>>(
            enc, ipose, tpose, focal, znear, zfar,
            W1, B1, W2, B2, W3, B3, rhalf);
        upsample_kernel<<<nout / 256, 256, 0, stream>>>(rhalf, out);
    }
}

// Round 7
// 727.055 us; speedup vs baseline: 2.2835x; 1.0957x over previous
//
#include <hip/hip_runtime.h>
#include <hip/hip_bf16.h>
#include <math.h>

// Problem constants (fixed by setup_inputs)
#define NS   2
#define NVIN 3
#define NVT  4
#define NC   16
#define ND   64
#define NH   96
#define NW   96
#define HWH  48          // half res h=w
#define SPR  64
#define DHW  (ND*NH*NW)  // 589824
#define NTILE (DHW / 64) // 9216 — NOT a power of two

typedef __attribute__((ext_vector_type(8))) short bfrag;   // 8 bf16 (4 VGPR)
typedef __attribute__((ext_vector_type(4))) float cfrag;   // 4 fp32 acc

#define MFMA16 __builtin_amdgcn_mfma_f32_16x16x32_bf16

__device__ __forceinline__ short f2bf(float x) {
    union { __hip_bfloat16 b; short s; } cv;
    cv.b = __float2bfloat16(x);
    return cv.s;
}
__device__ __forceinline__ float bf2f(short s) {
    union { unsigned int u; float f; } cv;
    cv.u = ((unsigned int)(unsigned short)s) << 16;
    return cv.f;
}

// Build hi/lo bf16 A-fragment from 8 consecutive fp32 in LDS.
// Verified layout (m120): A[m=lane&15][k=(lane>>4)*8+j], j=0..7.
__device__ __forceinline__ void mk_frag(const float* p, bfrag& ah, bfrag& al) {
    float4 v0 = *(const float4*)p;
    float4 v1 = *(const float4*)(p + 4);
    float e[8] = {v0.x, v0.y, v0.z, v0.w, v1.x, v1.y, v1.z, v1.w};
    #pragma unroll
    for (int j = 0; j < 8; j++) {
        short h = f2bf(e[j]);
        ah[j] = h;
        al[j] = f2bf(e[j] - bf2f(h));
    }
}

// ---------------------------------------------------------------------------
// Weight-fragment prep: split W1/W2/W3 into bf16 hi/lo, stored fragment-linear
// so each lane loads its whole B-fragment with one dwordx4.
// Frag ids: 0..3   L1 (kt=0, nt=f)          B[k][n]=W1[k*64+n], k<16 else 0
//           4..11  L2 kt=(f-4)>>2 nt=(f-4)&3 B=W2[k*64+n]
//           12..15 L3 kt=(f-12)>>1 nt=(f-12)&1 B=W3[k*17+n], n<17 else 0
// B-frag element (lane L, j): k = kt*32 + (L>>4)*8 + j, n = nt*16 + (L&15)
// ---------------------------------------------------------------------------
__global__ __launch_bounds__(256) void wprep_kernel(
    const float* __restrict__ W1, const float* __restrict__ W2,
    const float* __restrict__ W3, short* __restrict__ whi, short* __restrict__ wlo)
{
    int t = blockIdx.x * 256 + threadIdx.x;   // 1024 total
    int f = t >> 6, L = t & 63;
    int q = L >> 4, li = L & 15;
    #pragma unroll
    for (int j = 0; j < 8; j++) {
        int kloc = q * 8 + j;                 // 0..31
        float w = 0.f;
        if (f < 4) {
            int n = f * 16 + li, k = kloc;
            if (k < 16) w = W1[k * 64 + n];
        } else if (f < 12) {
            int kt = (f - 4) >> 2, nt = (f - 4) & 3;
            w = W2[(kt * 32 + kloc) * 64 + nt * 16 + li];
        } else {
            int kt = (f - 12) >> 1, nt = (f - 12) & 1;
            int n = nt * 16 + li;
            if (n < 17) w = W3[(kt * 32 + kloc) * 17 + n];
        }
        short h = f2bf(w);
        whi[(f * 64 + L) * 8 + j] = h;
        wlo[(f * 64 + L) * 8 + j] = f2bf(w - bf2f(h));
    }
}

// ---------------------------------------------------------------------------
// LDS-tiled transpose enc [6][16][DHW] -> enc_t [6][DHW][16].
// ---------------------------------------------------------------------------
__global__ __launch_bounds__(256) void transpose_kernel(
    const float* __restrict__ in, float* __restrict__ out)
{
    __shared__ float tile[NC][64 + 4];
    const int t   = threadIdx.x;
    const int blk = blockIdx.x;
    const int vox0 = (blk % NTILE) * 64;
    const int sv   = blk / NTILE;

    const int c  = t >> 4;
    const int vg = (t & 15) * 4;
    const float* src = in + ((size_t)sv * NC + c) * DHW + vox0 + vg;
    float4 v = *(const float4*)src;
    tile[c][vg + 0] = v.x; tile[c][vg + 1] = v.y;
    tile[c][vg + 2] = v.z; tile[c][vg + 3] = v.w;
    __syncthreads();

    const int ov = t >> 2;
    const int oc = (t & 3) * 4;
    float4 w = make_float4(tile[oc + 0][ov], tile[oc + 1][ov],
                           tile[oc + 2][ov], tile[oc + 3][ov]);
    float* dst = out + ((size_t)sv * DHW + vox0 + ov) * NC + oc;
    *(float4*)dst = w;
}

// ---------------------------------------------------------------------------
// Fused render with MFMA MLP. One wave per ray, lane = depth sample.
// MLP = per-wave GEMMs in bf16 hi/lo 3-product (fp32-accurate):
//   D += Al*Bh + Ah*Bl + Ah*Bh  on v_mfma_f32_16x16x32_bf16.
// LDS tile 64x36 fp32 per wave carries C-layout -> A-layout between layers,
// K-chunked by 32 so one tile serves X/H1/H2/O.
// ---------------------------------------------------------------------------
__global__ __launch_bounds__(256) void render_mfma_kernel(
    const float* __restrict__ enc_t,
    const float* __restrict__ ipose,
    const float* __restrict__ tpose,
    const float* __restrict__ focal_p,
    const float* __restrict__ znear_p,
    const float* __restrict__ zfar_p,
    const short* __restrict__ whi, const short* __restrict__ wlo,
    const float* __restrict__ B1, const float* __restrict__ B2,
    const float* __restrict__ B3,
    float* __restrict__ rhalf)
{
    const int lane = threadIdx.x & 63;
    const int ray  = blockIdx.x * 4 + (threadIdx.x >> 6);
    const int px   = ray % HWH;
    const int py   = (ray / HWH) % HWH;
    const int b    = ray / (HWH * HWH);
    const int s    = b >> 2;

    const float focal = focal_p[0];
    const float znear = znear_p[0];
    const float zfar  = zfar_p[0];

    // ---- ray generation ----
    const float* P = tpose + b * 16;
    float ysc = ((py + 0.5f) / (float)HWH) * 2.f - 1.f;
    float xsc = ((px + 0.5f) / (float)HWH) * 2.f - 1.f;
    float dcx = xsc / focal, dcy = -ysc / focal, dcz = -1.f;
    float dirx = P[0]*dcx + P[1]*dcy + P[2]*dcz;
    float diry = P[4]*dcx + P[5]*dcy + P[6]*dcz;
    float dirz = P[8]*dcx + P[9]*dcy + P[10]*dcz;
    float ox = P[3], oy = P[7], oz = P[11];

    float tv  = znear + (zfar - znear) * ((float)lane / (float)(SPR - 1));
    float ptx = ox + tv * dirx, pty = oy + tv * diry, ptz = oz + tv * dirz;

    float feats[NC];
    #pragma unroll
    for (int c = 0; c < NC; c++) feats[c] = 0.f;

    const float minz = focal * znear, maxz = focal * zfar;

    // ---- 3-view trilinear gather (channel-last: 64B per corner) ----
    for (int v = 0; v < NVIN; v++) {
        const float* E = ipose + (s * NVIN + v) * 16;
        float qx = ptx - E[3], qy = pty - E[7], qz = ptz - E[11];
        float lx = E[0]*qx + E[4]*qy + E[8]*qz;
        float ly = E[1]*qx + E[5]*qy + E[9]*qz;
        float lz = E[2]*qx + E[6]*qy + E[10]*qz;
        float zz = -lz;
        float u  = lx / zz * focal;
        float vv = ly / zz * focal;
        float wd = 2.f * (zz - minz) / (maxz - minz) - 1.f;
        float ix = ((u   + 1.f) * NW - 1.f) * 0.5f;
        float iy = ((-vv + 1.f) * NH - 1.f) * 0.5f;
        float iz = ((-wd + 1.f) * ND - 1.f) * 0.5f;
        float x0 = floorf(ix), y0 = floorf(iy), z0 = floorf(iz);

        float wgt[8]; int idx[8];
        #pragma unroll
        for (int k = 0; k < 8; k++) {
            float xc = x0 + (k & 1), yc = y0 + ((k >> 1) & 1), zc = z0 + (k >> 2);
            float wt = (1.f - fabsf(ix - xc)) * (1.f - fabsf(iy - yc)) * (1.f - fabsf(iz - zc));
            bool valid = (xc >= 0.f) && (xc < (float)NW) &&
                         (yc >= 0.f) && (yc < (float)NH) &&
                         (zc >= 0.f) && (zc < (float)ND);
            wgt[k] = valid ? wt : 0.f;
            int xi = min(max((int)xc, 0), NW - 1);
            int yi = min(max((int)yc, 0), NH - 1);
            int zi = min(max((int)zc, 0), ND - 1);
            idx[k] = (zi * NH + yi) * NW + xi;
        }
        const float* VB = enc_t + (size_t)(s * NVIN + v) * DHW * NC;
        #pragma unroll
        for (int k = 0; k < 8; k++) {
            const float* p = VB + (size_t)idx[k] * NC;
            float4 a0 = *(const float4*)(p);
            float4 a1 = *(const float4*)(p + 4);
            float4 a2 = *(const float4*)(p + 8);
            float4 a3 = *(const float4*)(p + 12);
            float w = wgt[k];
            feats[0]  += w * a0.x; feats[1]  += w * a0.y;
            feats[2]  += w * a0.z; feats[3]  += w * a0.w;
            feats[4]  += w * a1.x; feats[5]  += w * a1.y;
            feats[6]  += w * a1.z; feats[7]  += w * a1.w;
            feats[8]  += w * a2.x; feats[9]  += w * a2.y;
            feats[10] += w * a2.z; feats[11] += w * a2.w;
            feats[12] += w * a3.x; feats[13] += w * a3.y;
            feats[14] += w * a3.z; feats[15] += w * a3.w;
        }
    }
    #pragma unroll
    for (int c = 0; c < NC; c++) feats[c] *= (1.f / 3.f);

    // ================= MFMA MLP =================
    __shared__ float sbuf[4][64][36];   // per-wave 64x36 fp32 tile (36.9 KB/block)
    float (*B)[36] = sbuf[threadIdx.x >> 6];
    const int li = lane & 15, q = lane >> 4;

    float b1v[4], b2v[4], b3v[2];
    #pragma unroll
    for (int nt = 0; nt < 4; nt++) { b1v[nt] = B1[nt*16 + li]; b2v[nt] = B2[nt*16 + li]; }
    b3v[0] = B3[li];
    b3v[1] = (li == 0) ? B3[16] : 0.f;

    // stage X rows (zero-pad K 16->32)
    *(float4*)&B[lane][0]  = make_float4(feats[0], feats[1], feats[2],  feats[3]);
    *(float4*)&B[lane][4]  = make_float4(feats[4], feats[5], feats[6],  feats[7]);
    *(float4*)&B[lane][8]  = make_float4(feats[8], feats[9], feats[10], feats[11]);
    *(float4*)&B[lane][12] = make_float4(feats[12], feats[13], feats[14], feats[15]);
    float4 z4 = make_float4(0.f, 0.f, 0.f, 0.f);
    *(float4*)&B[lane][16] = z4; *(float4*)&B[lane][20] = z4;
    *(float4*)&B[lane][24] = z4; *(float4*)&B[lane][28] = z4;
    __syncthreads();

    bfrag xah[4], xal[4];
    #pragma unroll
    for (int mt = 0; mt < 4; mt++)
        mk_frag(&B[mt*16 + li][q*8], xah[mt], xal[mt]);

    cfrag zc = {0.f, 0.f, 0.f, 0.f};
    cfrag h2acc[4][4];
    #pragma unroll
    for (int mt = 0; mt < 4; mt++)
        #pragma unroll
        for (int nt = 0; nt < 4; nt++) h2acc[mt][nt] = zc;

    #pragma unroll
    for (int c1 = 0; c1 < 2; c1++) {
        // layer1: H1 tiles nt = 2*c1+nt2 (K=32 incl. zero pad)
        cfrag h1[4][2];
        #pragma unroll
        for (int nt2 = 0; nt2 < 2; nt2++) {
            int f = 2*c1 + nt2;
            bfrag bh = *(const bfrag*)(whi + (f*64 + lane)*8);
            bfrag bl = *(const bfrag*)(wlo + (f*64 + lane)*8);
            #pragma unroll
            for (int mt = 0; mt < 4; mt++) {
                cfrag a = zc;
                a = MFMA16(xal[mt], bh, a, 0, 0, 0);
                a = MFMA16(xah[mt], bl, a, 0, 0, 0);
                a = MFMA16(xah[mt], bh, a, 0, 0, 0);
                h1[mt][nt2] = a;
            }
        }
        __syncthreads();
        // C-layout (row = mt*16+q*4+r, col = nt2*16+li) -> LDS, bias+relu
        #pragma unroll
        for (int mt = 0; mt < 4; mt++)
            #pragma unroll
            for (int nt2 = 0; nt2 < 2; nt2++)
                #pragma unroll
                for (int r = 0; r < 4; r++)
                    B[mt*16 + q*4 + r][nt2*16 + li] =
                        fmaxf(h1[mt][nt2][r] + b1v[2*c1 + nt2], 0.f);
        __syncthreads();
        // layer2: K-chunk c1
        bfrag hah[4], hal[4];
        #pragma unroll
        for (int mt = 0; mt < 4; mt++)
            mk_frag(&B[mt*16 + li][q*8], hah[mt], hal[mt]);
        #pragma unroll
        for (int nt = 0; nt < 4; nt++) {
            int f = 4 + c1*4 + nt;
            bfrag bh = *(const bfrag*)(whi + (f*64 + lane)*8);
            bfrag bl = *(const bfrag*)(wlo + (f*64 + lane)*8);
            #pragma unroll
            for (int mt = 0; mt < 4; mt++) {
                cfrag a = h2acc[mt][nt];
                a = MFMA16(hal[mt], bh, a, 0, 0, 0);
                a = MFMA16(hah[mt], bl, a, 0, 0, 0);
                a = MFMA16(hah[mt], bh, a, 0, 0, 0);
                h2acc[mt][nt] = a;
            }
        }
    }

    // layer3: O = relu(H2+b2) @ W3, K-chunked by 32
    cfrag oacc[4][2];
    #pragma unroll
    for (int mt = 0; mt < 4; mt++)
        #pragma unroll
        for (int nt = 0; nt < 2; nt++) oacc[mt][nt] = zc;

    #pragma unroll
    for (int c2 = 0; c2 < 2; c2++) {
        __syncthreads();
        #pragma unroll
        for (int mt = 0; mt < 4; mt++)
            #pragma unroll
            for (int nt2 = 0; nt2 < 2; nt2++)
                #pragma unroll
                for (int r = 0; r < 4; r++)
                    B[mt*16 + q*4 + r][nt2*16 + li] =
                        fmaxf(h2acc[mt][2*c2 + nt2][r] + b2v[2*c2 + nt2], 0.f);
        __syncthreads();
        bfrag hah[4], hal[4];
        #pragma unroll
        for (int mt = 0; mt < 4; mt++)
            mk_frag(&B[mt*16 + li][q*8], hah[mt], hal[mt]);
        #pragma unroll
        for (int nt = 0; nt < 2; nt++) {
            int f = 12 + c2*2 + nt;
            bfrag bh = *(const bfrag*)(whi + (f*64 + lane)*8);
            bfrag bl = *(const bfrag*)(wlo + (f*64 + lane)*8);
            #pragma unroll
            for (int mt = 0; mt < 4; mt++) {
                cfrag a = oacc[mt][nt];
                a = MFMA16(hal[mt], bh, a, 0, 0, 0);
                a = MFMA16(hah[mt], bl, a, 0, 0, 0);
                a = MFMA16(hah[mt], bh, a, 0, 0, 0);
                oacc[mt][nt] = a;
            }
        }
    }

    // O (C-layout) -> LDS -> per-lane (lane = its own sample row)
    __syncthreads();
    #pragma unroll
    for (int mt = 0; mt < 4; mt++)
        #pragma unroll
        for (int nt = 0; nt < 2; nt++) {
            int ch = nt*16 + li;
            if (ch < 17) {
                #pragma unroll
                for (int r = 0; r < 4; r++)
                    B[mt*16 + q*4 + r][ch] = oacc[mt][nt][r] + b3v[nt];
            }
        }
    __syncthreads();
    float4 o0 = *(float4*)&B[lane][0];
    float4 o1 = *(float4*)&B[lane][4];
    float4 o2 = *(float4*)&B[lane][8];
    float4 o3 = *(float4*)&B[lane][12];
    float o16 = B[lane][16];

    float density = fmaxf(o0.x, 0.f);
    float orgb[16] = {o0.y, o0.z, o0.w, o1.x, o1.y, o1.z, o1.w, o2.x,
                      o2.y, o2.z, o2.w, o3.x, o3.y, o3.z, o3.w, o16};

    // ---- per-ray compositing ----
    float tn = znear + (zfar - znear) * ((float)(lane + 1) / (float)(SPR - 1));
    float delta = (lane < SPR - 1) ? (tn - tv) : 1e10f;
    float sigdel = density * delta;
    float alpha = 1.f - expf(-sigdel);
    float csum = sigdel;
    #pragma unroll
    for (int off = 1; off < 64; off <<= 1) {
        float nb = __shfl_up(csum, off, 64);
        if (lane >= off) csum += nb;
    }
    float wray = alpha * expf(-csum);

    #pragma unroll
    for (int c = 0; c < NC; c++) {
        float val = wray * (feats[c] + orgb[c]);
        #pragma unroll
        for (int off = 32; off >= 1; off >>= 1)
            val += __shfl_down(val, off, 64);
        if (lane == 0)
            rhalf[((b * NC + c) * HWH + py) * HWH + px] = val;
    }
}

// ---------------------------------------------------------------------------
// Scalar MLP+composite (R6-proven) — fallback path only.
// ---------------------------------------------------------------------------
__device__ __forceinline__ void mlp_and_composite(
    const float feats[NC], int lane, int b, int py, int px,
    float tv, float znear, float zfar,
    const float* __restrict__ W1, const float* __restrict__ B1,
    const float* __restrict__ W2, const float* __restrict__ B2,
    const float* __restrict__ W3, const float* __restrict__ B3,
    float* __restrict__ rhalf)
{
    float outa[17];
    #pragma unroll
    for (int c = 0; c < 17; c++) outa[c] = B3[c];

    for (int kc = 0; kc < 4; kc++) {
        float h2c[16];
        #pragma unroll
        for (int k = 0; k < 16; k++) h2c[k] = B2[kc * 16 + k];
        #pragma unroll 4
        for (int j = 0; j < 64; j++) {
            float a = B1[j];
            #pragma unroll
            for (int i = 0; i < NC; i++) a += feats[i] * W1[i * 64 + j];
            a = fmaxf(a, 0.f);
            const float* w2p = W2 + j * 64 + kc * 16;
            #pragma unroll
            for (int k = 0; k < 16; k++) h2c[k] += a * w2p[k];
        }
        #pragma unroll
        for (int k = 0; k < 16; k++) {
            float hv = fmaxf(h2c[k], 0.f);
            const float* w3p = W3 + (kc * 16 + k) * 17;
            #pragma unroll
            for (int c = 0; c < 17; c++) outa[c] += hv * w3p[c];
        }
    }
    float density = fmaxf(outa[0], 0.f);

    float tn = znear + (zfar - znear) * ((float)(lane + 1) / (float)(SPR - 1));
    float delta = (lane < SPR - 1) ? (tn - tv) : 1e10f;
    float sigdel = density * delta;
    float alpha = 1.f - expf(-sigdel);
    float csum = sigdel;
    #pragma unroll
    for (int off = 1; off < 64; off <<= 1) {
        float nb = __shfl_up(csum, off, 64);
        if (lane >= off) csum += nb;
    }
    float wray = alpha * expf(-csum);

    #pragma unroll
    for (int c = 0; c < NC; c++) {
        float val = wray * (feats[c] + outa[1 + c]);
        #pragma unroll
        for (int off = 32; off >= 1; off >>= 1)
            val += __shfl_down(val, off, 64);
        if (lane == 0)
            rhalf[((b * NC + c) * HWH + py) * HWH + px] = val;
    }
}

__global__ __launch_bounds__(256) void render_kernel(
    const float* __restrict__ enc,
    const float* __restrict__ ipose,
    const float* __restrict__ tpose,
    const float* __restrict__ focal_p,
    const float* __restrict__ znear_p,
    const float* __restrict__ zfar_p,
    const float* __restrict__ W1, const float* __restrict__ B1,
    const float* __restrict__ W2, const float* __restrict__ B2,
    const float* __restrict__ W3, const float* __restrict__ B3,
    float* __restrict__ rhalf)
{
    const int lane = threadIdx.x & 63;
    const int ray  = blockIdx.x * 4 + (threadIdx.x >> 6);
    const int px   = ray % HWH;
    const int py   = (ray / HWH) % HWH;
    const int b    = ray / (HWH * HWH);
    const int s    = b >> 2;

    const float focal = focal_p[0];
    const float znear = znear_p[0];
    const float zfar  = zfar_p[0];

    const float* P = tpose + b * 16;
    float ysc = ((py + 0.5f) / (float)HWH) * 2.f - 1.f;
    float xsc = ((px + 0.5f) / (float)HWH) * 2.f - 1.f;
    float dcx = xsc / focal, dcy = -ysc / focal, dcz = -1.f;
    float dirx = P[0]*dcx + P[1]*dcy + P[2]*dcz;
    float diry = P[4]*dcx + P[5]*dcy + P[6]*dcz;
    float dirz = P[8]*dcx + P[9]*dcy + P[10]*dcz;
    float ox = P[3], oy = P[7], oz = P[11];

    float tv  = znear + (zfar - znear) * ((float)lane / (float)(SPR - 1));
    float ptx = ox + tv * dirx, pty = oy + tv * diry, ptz = oz + tv * dirz;

    float feats[NC];
    #pragma unroll
    for (int c = 0; c < NC; c++) feats[c] = 0.f;

    const float minz = focal * znear, maxz = focal * zfar;

    for (int v = 0; v < NVIN; v++) {
        const float* E = ipose + (s * NVIN + v) * 16;
        float qx = ptx - E[3], qy = pty - E[7], qz = ptz - E[11];
        float lx = E[0]*qx + E[4]*qy + E[8]*qz;
        float ly = E[1]*qx + E[5]*qy + E[9]*qz;
        float lz = E[2]*qx + E[6]*qy + E[10]*qz;
        float zz = -lz;
        float u  = lx / zz * focal;
        float vv = ly / zz * focal;
        float wd = 2.f * (zz - minz) / (maxz - minz) - 1.f;
        float ix = ((u   + 1.f) * NW - 1.f) * 0.5f;
        float iy = ((-vv + 1.f) * NH - 1.f) * 0.5f;
        float iz = ((-wd + 1.f) * ND - 1.f) * 0.5f;
        float x0 = floorf(ix), y0 = floorf(iy), z0 = floorf(iz);

        float wgt[8]; int idx[8];
        #pragma unroll
        for (int k = 0; k < 8; k++) {
            float xc = x0 + (k & 1), yc = y0 + ((k >> 1) & 1), zc = z0 + (k >> 2);
            float wt = (1.f - fabsf(ix - xc)) * (1.f - fabsf(iy - yc)) * (1.f - fabsf(iz - zc));
            bool valid = (xc >= 0.f) && (xc < (float)NW) &&
                         (yc >= 0.f) && (yc < (float)NH) &&
                         (zc >= 0.f) && (zc < (float)ND);
            wgt[k] = valid ? wt : 0.f;
            int xi = min(max((int)xc, 0), NW - 1);
            int yi = min(max((int)yc, 0), NH - 1);
            int zi = min(max((int)zc, 0), ND - 1);
            idx[k] = (zi * NH + yi) * NW + xi;
        }
        const float* VB = enc + (size_t)(s * NVIN + v) * NC * DHW;
        #pragma unroll
        for (int c = 0; c < NC; c++) {
            const float* vc = VB + c * DHW;
            float acc = 0.f;
            #pragma unroll
            for (int k = 0; k < 8; k++) acc += wgt[k] * vc[idx[k]];
            feats[c] += acc;
        }
    }
    #pragma unroll
    for (int c = 0; c < NC; c++) feats[c] *= (1.f / 3.f);

    mlp_and_composite(feats, lane, b, py, px, tv, znear, zfar,
                      W1, B1, W2, B2, W3, B3, rhalf);
}

// 2x bilinear upsample, align_corners=True.
__global__ __launch_bounds__(256) void upsample_kernel(
    const float* __restrict__ in, float* __restrict__ out)
{
    int tid = blockIdx.x * 256 + threadIdx.x;
    int ox = tid % NW;
    int oy = (tid / NW) % NH;
    int c  = (tid / (NW * NH)) % NC;
    int b  = tid / (NW * NH * NC);
    const float sc = (float)((HWH - 1) / (double)(NH - 1)); // 47/95
    float pyf = oy * sc;
    float pxf = ox * sc;
    int y0 = (int)floorf(pyf); int y1 = min(y0 + 1, HWH - 1); float fy = pyf - y0;
    int x0 = (int)floorf(pxf); int x1 = min(x0 + 1, HWH - 1); float fx = pxf - x0;
    const float* src = in + (b * NC + c) * HWH * HWH;
    float v00 = src[y0 * HWH + x0], v01 = src[y0 * HWH + x1];
    float v10 = src[y1 * HWH + x0], v11 = src[y1 * HWH + x1];
    float gl = v00 * (1.f - fy) + v10 * fy;
    float gr = v01 * (1.f - fy) + v11 * fy;
    out[tid] = gl * (1.f - fx) + gr * fx;
}

extern "C" void kernel_launch(void* const* d_in, const int* in_sizes, int n_in,
                              void* d_out, int out_size, void* d_ws, size_t ws_size,
                              hipStream_t stream) {
    const float* enc   = (const float*)d_in[0];
    const float* ipose = (const float*)d_in[1];
    const float* tpose = (const float*)d_in[2];
    const float* focal = (const float*)d_in[3];
    const float* znear = (const float*)d_in[4];
    const float* zfar  = (const float*)d_in[5];
    const float* W1 = (const float*)d_in[7];
    const float* B1 = (const float*)d_in[8];
    const float* W2 = (const float*)d_in[9];
    const float* B2 = (const float*)d_in[10];
    const float* W3 = (const float*)d_in[11];
    const float* B3 = (const float*)d_in[12];

    float* out = (float*)d_out;
    const int nrays = NS * NVT * HWH * HWH;              // 18432
    const int nout  = NS * NVT * NC * NH * NW;           // 1179648
    const size_t enc_t_bytes = (size_t)NS * NVIN * NC * DHW * 4;   // 226.5 MB
    const size_t rhalf_bytes = (size_t)NS * NVT * NC * HWH * HWH * 4;
    const size_t wfrag_bytes = 16 * 64 * 8 * sizeof(short);        // 16 KB each

    if (ws_size >= enc_t_bytes + rhalf_bytes + 2 * wfrag_bytes) {
        float* enc_t = (float*)d_ws;
        float* rhalf = (float*)((char*)d_ws + enc_t_bytes);
        short* whi   = (short*)((char*)d_ws + enc_t_bytes + rhalf_bytes);
        short* wlo   = whi + 16 * 64 * 8;

        wprep_kernel<<<4, 256, 0, stream>>>(W1, W2, W3, whi, wlo);
        const int ntiles = NS * NVIN * NTILE;            // 55296 blocks
        transpose_kernel<<<ntiles, 256, 0, stream>>>(enc, enc_t);
        render_mfma_kernel<<<nrays / 4, 256, 0, stream>>>(
            enc_t, ipose, tpose, focal, znear, zfar,
            whi, wlo, B1, B2, B3, rhalf);
        upsample_kernel<<<nout / 256, 256, 0, stream>>>(rhalf, out);
    } else {
        float* rhalf = (float*)d_ws;
        render_kernel<<<nrays / 4, 256, 0, stream>>>(
            enc, ipose, tpose, focal, znear, zfar,
            W1, B1, W2, B2, W3, B3, rhalf);
        upsample_kernel<<<nout / 256, 256, 0, stream>>>(rhalf, out);
    }
}

// Round 8
// 616.877 us; speedup vs baseline: 2.6914x; 1.1786x over previous
//
#include <hip/hip_runtime.h>
#include <hip/hip_bf16.h>
#include <math.h>

// Problem constants (fixed by setup_inputs)
#define NS   2
#define NVIN 3
#define NVT  4
#define NC   16
#define ND   64
#define NH   96
#define NW   96
#define HWH  48          // half res h=w
#define SPR  64
#define DHW  (ND*NH*NW)  // 589824
#define NTILE (DHW / 64) // 9216 — NOT a power of two
#define NSAMP (NS*NVT*HWH*HWH*SPR)   // 1179648 samples

typedef __attribute__((ext_vector_type(8))) short bfrag;   // 8 bf16 (4 VGPR)
typedef __attribute__((ext_vector_type(4))) float cfrag;   // 4 fp32 acc

#define MFMA16 __builtin_amdgcn_mfma_f32_16x16x32_bf16

__device__ __forceinline__ short f2bf(float x) {
    union { __hip_bfloat16 b; short s; } cv;
    cv.b = __float2bfloat16(x);
    return cv.s;
}
__device__ __forceinline__ float bf2f(short s) {
    union { unsigned int u; float f; } cv;
    cv.u = ((unsigned int)(unsigned short)s) << 16;
    return cv.f;
}

// Build hi/lo bf16 A-fragment from 8 consecutive fp32 (LDS or global).
// Verified layout (m120): A[m=lane&15][k=(lane>>4)*8+j], j=0..7.
__device__ __forceinline__ void mk_frag(const float* p, bfrag& ah, bfrag& al) {
    float4 v0 = *(const float4*)p;
    float4 v1 = *(const float4*)(p + 4);
    float e[8] = {v0.x, v0.y, v0.z, v0.w, v1.x, v1.y, v1.z, v1.w};
    #pragma unroll
    for (int j = 0; j < 8; j++) {
        short h = f2bf(e[j]);
        ah[j] = h;
        al[j] = f2bf(e[j] - bf2f(h));
    }
}

// ---------------------------------------------------------------------------
// Weight-fragment prep (R7-verified): split W1/W2/W3 into bf16 hi/lo,
// fragment-linear so each lane loads its B-fragment with one dwordx4.
// ---------------------------------------------------------------------------
__global__ __launch_bounds__(256) void wprep_kernel(
    const float* __restrict__ W1, const float* __restrict__ W2,
    const float* __restrict__ W3, short* __restrict__ whi, short* __restrict__ wlo)
{
    int t = blockIdx.x * 256 + threadIdx.x;   // 1024 total
    int f = t >> 6, L = t & 63;
    int q = L >> 4, li = L & 15;
    #pragma unroll
    for (int j = 0; j < 8; j++) {
        int kloc = q * 8 + j;                 // 0..31
        float w = 0.f;
        if (f < 4) {
            int n = f * 16 + li, k = kloc;
            if (k < 16) w = W1[k * 64 + n];
        } else if (f < 12) {
            int kt = (f - 4) >> 2, nt = (f - 4) & 3;
            w = W2[(kt * 32 + kloc) * 64 + nt * 16 + li];
        } else {
            int kt = (f - 12) >> 1, nt = (f - 12) & 1;
            int n = nt * 16 + li;
            if (n < 17) w = W3[(kt * 32 + kloc) * 17 + n];
        }
        short h = f2bf(w);
        whi[(f * 64 + L) * 8 + j] = h;
        wlo[(f * 64 + L) * 8 + j] = f2bf(w - bf2f(h));
    }
}

// ---------------------------------------------------------------------------
// LDS-tiled transpose enc [6][16][DHW] -> enc_t [6][DHW][16].
// ---------------------------------------------------------------------------
__global__ __launch_bounds__(256) void transpose_kernel(
    const float* __restrict__ in, float* __restrict__ out)
{
    __shared__ float tile[NC][64 + 4];
    const int t   = threadIdx.x;
    const int blk = blockIdx.x;
    const int vox0 = (blk % NTILE) * 64;
    const int sv   = blk / NTILE;

    const int c  = t >> 4;
    const int vg = (t & 15) * 4;
    const float* src = in + ((size_t)sv * NC + c) * DHW + vox0 + vg;
    float4 v = *(const float4*)src;
    tile[c][vg + 0] = v.x; tile[c][vg + 1] = v.y;
    tile[c][vg + 2] = v.z; tile[c][vg + 3] = v.w;
    __syncthreads();

    const int ov = t >> 2;
    const int oc = (t & 3) * 4;
    float4 w = make_float4(tile[oc + 0][ov], tile[oc + 1][ov],
                           tile[oc + 2][ov], tile[oc + 3][ov]);
    float* dst = out + ((size_t)sv * DHW + vox0 + ov) * NC + oc;
    *(float4*)dst = w;
}

// ---------------------------------------------------------------------------
// Quad-cooperative gather: 4 lanes per sample, lane c4 loads channels
// 4*c4..4*c4+3 (16 B). A quad's 4 loads hit ONE 64 B voxel line -> the TA
// processes each (sample,corner) line once instead of 4x (R7: 113M line
// transactions; now 28M). Writes X[sample][16] to ws.
// ---------------------------------------------------------------------------
__global__ __launch_bounds__(256) void gather_kernel(
    const float* __restrict__ enc_t,
    const float* __restrict__ ipose,
    const float* __restrict__ tpose,
    const float* __restrict__ focal_p,
    const float* __restrict__ znear_p,
    const float* __restrict__ zfar_p,
    float* __restrict__ xbuf)
{
    const int tid = blockIdx.x * 256 + threadIdx.x;  // NSAMP*4 threads
    const int c4  = tid & 3;
    const int smp = tid >> 2;
    const int d   = smp & 63;            // depth sample
    const int ray = smp >> 6;
    const int px  = ray % HWH;
    const int py  = (ray / HWH) % HWH;
    const int b   = ray / (HWH * HWH);
    const int s   = b >> 2;

    const float focal = focal_p[0];
    const float znear = znear_p[0];
    const float zfar  = zfar_p[0];

    const float* P = tpose + b * 16;
    float ysc = ((py + 0.5f) / (float)HWH) * 2.f - 1.f;
    float xsc = ((px + 0.5f) / (float)HWH) * 2.f - 1.f;
    float dcx = xsc / focal, dcy = -ysc / focal, dcz = -1.f;
    float dirx = P[0]*dcx + P[1]*dcy + P[2]*dcz;
    float diry = P[4]*dcx + P[5]*dcy + P[6]*dcz;
    float dirz = P[8]*dcx + P[9]*dcy + P[10]*dcz;

    float tv  = znear + (zfar - znear) * ((float)d / (float)(SPR - 1));
    float ptx = P[3] + tv * dirx, pty = P[7] + tv * diry, ptz = P[11] + tv * dirz;

    const float minz = focal * znear, maxz = focal * zfar;
    float f0 = 0.f, f1 = 0.f, f2 = 0.f, f3 = 0.f;

    for (int v = 0; v < NVIN; v++) {
        const float* E = ipose + (s * NVIN + v) * 16;
        float qx = ptx - E[3], qy = pty - E[7], qz = ptz - E[11];
        float lx = E[0]*qx + E[4]*qy + E[8]*qz;
        float ly = E[1]*qx + E[5]*qy + E[9]*qz;
        float lz = E[2]*qx + E[6]*qy + E[10]*qz;
        float zz = -lz;
        float u  = lx / zz * focal;
        float vv = ly / zz * focal;
        float wd = 2.f * (zz - minz) / (maxz - minz) - 1.f;
        float ix = ((u   + 1.f) * NW - 1.f) * 0.5f;
        float iy = ((-vv + 1.f) * NH - 1.f) * 0.5f;
        float iz = ((-wd + 1.f) * ND - 1.f) * 0.5f;
        float x0 = floorf(ix), y0 = floorf(iy), z0 = floorf(iz);

        const float* VB = enc_t + (size_t)(s * NVIN + v) * DHW * NC;
        #pragma unroll
        for (int k = 0; k < 8; k++) {
            float xc = x0 + (k & 1), yc = y0 + ((k >> 1) & 1), zc = z0 + (k >> 2);
            float wt = (1.f - fabsf(ix - xc)) * (1.f - fabsf(iy - yc)) * (1.f - fabsf(iz - zc));
            bool valid = (xc >= 0.f) && (xc < (float)NW) &&
                         (yc >= 0.f) && (yc < (float)NH) &&
                         (zc >= 0.f) && (zc < (float)ND);
            float w = valid ? wt : 0.f;
            int xi = min(max((int)xc, 0), NW - 1);
            int yi = min(max((int)yc, 0), NH - 1);
            int zi = min(max((int)zc, 0), ND - 1);
            int idx = (zi * NH + yi) * NW + xi;
            float4 a = *(const float4*)(VB + (size_t)idx * NC + c4 * 4);
            f0 += w * a.x; f1 += w * a.y; f2 += w * a.z; f3 += w * a.w;
        }
    }
    const float inv3 = 1.f / 3.f;
    ((float4*)xbuf)[tid] = make_float4(f0 * inv3, f1 * inv3, f2 * inv3, f3 * inv3);
}

// ---------------------------------------------------------------------------
// MFMA MLP + composite (R7-verified pipeline, A-frags from global xbuf).
// One wave per ray; block = 4 rays. bf16 hi/lo 3-product = fp32-accurate.
// ---------------------------------------------------------------------------
__global__ __launch_bounds__(256) void mlp_kernel(
    const float* __restrict__ xbuf,
    const float* __restrict__ znear_p,
    const float* __restrict__ zfar_p,
    const short* __restrict__ whi, const short* __restrict__ wlo,
    const float* __restrict__ B1, const float* __restrict__ B2,
    const float* __restrict__ B3,
    float* __restrict__ rhalf)
{
    const int lane = threadIdx.x & 63;
    const int ray  = blockIdx.x * 4 + (threadIdx.x >> 6);
    const int px   = ray % HWH;
    const int py   = (ray / HWH) % HWH;
    const int b    = ray / (HWH * HWH);

    const float znear = znear_p[0];
    const float zfar  = zfar_p[0];

    __shared__ float sbuf[4][64][36];   // per-wave 64x36 staging (36.9 KB)
    float (*B)[36] = sbuf[threadIdx.x >> 6];
    const int li = lane & 15, q = lane >> 4;
    const float* X = xbuf + (size_t)ray * 64 * NC;   // this ray's 64x16 rows

    float b1v[4], b2v[4], b3v[2];
    #pragma unroll
    for (int nt = 0; nt < 4; nt++) { b1v[nt] = B1[nt*16 + li]; b2v[nt] = B2[nt*16 + li]; }
    b3v[0] = B3[li];
    b3v[1] = (li == 0) ? B3[16] : 0.f;

    // layer-1 A-frags straight from global X (K=16; q>=2 lanes are zero pad)
    bfrag xah[4], xal[4];
    bfrag zb = {0,0,0,0,0,0,0,0};
    #pragma unroll
    for (int mt = 0; mt < 4; mt++) {
        if (q < 2) mk_frag(X + (mt*16 + li) * NC + q * 8, xah[mt], xal[mt]);
        else { xah[mt] = zb; xal[mt] = zb; }
    }

    cfrag zc = {0.f, 0.f, 0.f, 0.f};
    cfrag h2acc[4][4];
    #pragma unroll
    for (int mt = 0; mt < 4; mt++)
        #pragma unroll
        for (int nt = 0; nt < 4; nt++) h2acc[mt][nt] = zc;

    #pragma unroll
    for (int c1 = 0; c1 < 2; c1++) {
        cfrag h1[4][2];
        #pragma unroll
        for (int nt2 = 0; nt2 < 2; nt2++) {
            int f = 2*c1 + nt2;
            bfrag bh = *(const bfrag*)(whi + (f*64 + lane)*8);
            bfrag bl = *(const bfrag*)(wlo + (f*64 + lane)*8);
            #pragma unroll
            for (int mt = 0; mt < 4; mt++) {
                cfrag a = zc;
                a = MFMA16(xal[mt], bh, a, 0, 0, 0);
                a = MFMA16(xah[mt], bl, a, 0, 0, 0);
                a = MFMA16(xah[mt], bh, a, 0, 0, 0);
                h1[mt][nt2] = a;
            }
        }
        __syncthreads();
        #pragma unroll
        for (int mt = 0; mt < 4; mt++)
            #pragma unroll
            for (int nt2 = 0; nt2 < 2; nt2++)
                #pragma unroll
                for (int r = 0; r < 4; r++)
                    B[mt*16 + q*4 + r][nt2*16 + li] =
                        fmaxf(h1[mt][nt2][r] + b1v[2*c1 + nt2], 0.f);
        __syncthreads();
        bfrag hah[4], hal[4];
        #pragma unroll
        for (int mt = 0; mt < 4; mt++)
            mk_frag(&B[mt*16 + li][q*8], hah[mt], hal[mt]);
        #pragma unroll
        for (int nt = 0; nt < 4; nt++) {
            int f = 4 + c1*4 + nt;
            bfrag bh = *(const bfrag*)(whi + (f*64 + lane)*8);
            bfrag bl = *(const bfrag*)(wlo + (f*64 + lane)*8);
            #pragma unroll
            for (int mt = 0; mt < 4; mt++) {
                cfrag a = h2acc[mt][nt];
                a = MFMA16(hal[mt], bh, a, 0, 0, 0);
                a = MFMA16(hah[mt], bl, a, 0, 0, 0);
                a = MFMA16(hah[mt], bh, a, 0, 0, 0);
                h2acc[mt][nt] = a;
            }
        }
    }

    cfrag oacc[4][2];
    #pragma unroll
    for (int mt = 0; mt < 4; mt++)
        #pragma unroll
        for (int nt = 0; nt < 2; nt++) oacc[mt][nt] = zc;

    #pragma unroll
    for (int c2 = 0; c2 < 2; c2++) {
        __syncthreads();
        #pragma unroll
        for (int mt = 0; mt < 4; mt++)
            #pragma unroll
            for (int nt2 = 0; nt2 < 2; nt2++)
                #pragma unroll
                for (int r = 0; r < 4; r++)
                    B[mt*16 + q*4 + r][nt2*16 + li] =
                        fmaxf(h2acc[mt][2*c2 + nt2][r] + b2v[2*c2 + nt2], 0.f);
        __syncthreads();
        bfrag hah[4], hal[4];
        #pragma unroll
        for (int mt = 0; mt < 4; mt++)
            mk_frag(&B[mt*16 + li][q*8], hah[mt], hal[mt]);
        #pragma unroll
        for (int nt = 0; nt < 2; nt++) {
            int f = 12 + c2*2 + nt;
            bfrag bh = *(const bfrag*)(whi + (f*64 + lane)*8);
            bfrag bl = *(const bfrag*)(wlo + (f*64 + lane)*8);
            #pragma unroll
            for (int mt = 0; mt < 4; mt++) {
                cfrag a = oacc[mt][nt];
                a = MFMA16(hal[mt], bh, a, 0, 0, 0);
                a = MFMA16(hah[mt], bl, a, 0, 0, 0);
                a = MFMA16(hah[mt], bh, a, 0, 0, 0);
                oacc[mt][nt] = a;
            }
        }
    }

    // O (C-layout) -> LDS -> per-lane (lane = its own sample row)
    __syncthreads();
    #pragma unroll
    for (int mt = 0; mt < 4; mt++)
        #pragma unroll
        for (int nt = 0; nt < 2; nt++) {
            int ch = nt*16 + li;
            if (ch < 17) {
                #pragma unroll
                for (int r = 0; r < 4; r++)
                    B[mt*16 + q*4 + r][ch] = oacc[mt][nt][r] + b3v[nt];
            }
        }
    __syncthreads();
    float4 o0 = *(float4*)&B[lane][0];
    float4 o1 = *(float4*)&B[lane][4];
    float4 o2 = *(float4*)&B[lane][8];
    float4 o3 = *(float4*)&B[lane][12];
    float o16 = B[lane][16];

    float density = fmaxf(o0.x, 0.f);
    float orgb[16] = {o0.y, o0.z, o0.w, o1.x, o1.y, o1.z, o1.w, o2.x,
                      o2.y, o2.z, o2.w, o3.x, o3.y, o3.z, o3.w, o16};

    // feats re-read from L2-hot xbuf (saves 16 live VGPRs across the MLP)
    float4 fx0 = *(const float4*)(X + lane * NC + 0);
    float4 fx1 = *(const float4*)(X + lane * NC + 4);
    float4 fx2 = *(const float4*)(X + lane * NC + 8);
    float4 fx3 = *(const float4*)(X + lane * NC + 12);
    float feats[16] = {fx0.x, fx0.y, fx0.z, fx0.w, fx1.x, fx1.y, fx1.z, fx1.w,
                       fx2.x, fx2.y, fx2.z, fx2.w, fx3.x, fx3.y, fx3.z, fx3.w};

    // ---- per-ray compositing ----
    float tv = znear + (zfar - znear) * ((float)lane / (float)(SPR - 1));
    float tn = znear + (zfar - znear) * ((float)(lane + 1) / (float)(SPR - 1));
    float delta = (lane < SPR - 1) ? (tn - tv) : 1e10f;
    float sigdel = density * delta;
    float alpha = 1.f - expf(-sigdel);
    float csum = sigdel;
    #pragma unroll
    for (int off = 1; off < 64; off <<= 1) {
        float nb = __shfl_up(csum, off, 64);
        if (lane >= off) csum += nb;
    }
    float wray = alpha * expf(-csum);

    #pragma unroll
    for (int c = 0; c < NC; c++) {
        float val = wray * (feats[c] + orgb[c]);
        #pragma unroll
        for (int off = 32; off >= 1; off >>= 1)
            val += __shfl_down(val, off, 64);
        if (lane == 0)
            rhalf[((b * NC + c) * HWH + py) * HWH + px] = val;
    }
}

// ---------------------------------------------------------------------------
// Scalar fallback (R6-proven) — only if ws too small.
// ---------------------------------------------------------------------------
__device__ __forceinline__ void mlp_and_composite(
    const float feats[NC], int lane, int b, int py, int px,
    float tv, float znear, float zfar,
    const float* __restrict__ W1, const float* __restrict__ B1,
    const float* __restrict__ W2, const float* __restrict__ B2,
    const float* __restrict__ W3, const float* __restrict__ B3,
    float* __restrict__ rhalf)
{
    float outa[17];
    #pragma unroll
    for (int c = 0; c < 17; c++) outa[c] = B3[c];
    for (int kc = 0; kc < 4; kc++) {
        float h2c[16];
        #pragma unroll
        for (int k = 0; k < 16; k++) h2c[k] = B2[kc * 16 + k];
        #pragma unroll 4
        for (int j = 0; j < 64; j++) {
            float a = B1[j];
            #pragma unroll
            for (int i = 0; i < NC; i++) a += feats[i] * W1[i * 64 + j];
            a = fmaxf(a, 0.f);
            const float* w2p = W2 + j * 64 + kc * 16;
            #pragma unroll
            for (int k = 0; k < 16; k++) h2c[k] += a * w2p[k];
        }
        #pragma unroll
        for (int k = 0; k < 16; k++) {
            float hv = fmaxf(h2c[k], 0.f);
            const float* w3p = W3 + (kc * 16 + k) * 17;
            #pragma unroll
            for (int c = 0; c < 17; c++) outa[c] += hv * w3p[c];
        }
    }
    float density = fmaxf(outa[0], 0.f);
    float tn = znear + (zfar - znear) * ((float)(lane + 1) / (float)(SPR - 1));
    float delta = (lane < SPR - 1) ? (tn - tv) : 1e10f;
    float sigdel = density * delta;
    float alpha = 1.f - expf(-sigdel);
    float csum = sigdel;
    #pragma unroll
    for (int off = 1; off < 64; off <<= 1) {
        float nb = __shfl_up(csum, off, 64);
        if (lane >= off) csum += nb;
    }
    float wray = alpha * expf(-csum);
    #pragma unroll
    for (int c = 0; c < NC; c++) {
        float val = wray * (feats[c] + outa[1 + c]);
        #pragma unroll
        for (int off = 32; off >= 1; off >>= 1)
            val += __shfl_down(val, off, 64);
        if (lane == 0)
            rhalf[((b * NC + c) * HWH + py) * HWH + px] = val;
    }
}

__global__ __launch_bounds__(256) void render_kernel(
    const float* __restrict__ enc,
    const float* __restrict__ ipose,
    const float* __restrict__ tpose,
    const float* __restrict__ focal_p,
    const float* __restrict__ znear_p,
    const float* __restrict__ zfar_p,
    const float* __restrict__ W1, const float* __restrict__ B1,
    const float* __restrict__ W2, const float* __restrict__ B2,
    const float* __restrict__ W3, const float* __restrict__ B3,
    float* __restrict__ rhalf)
{
    const int lane = threadIdx.x & 63;
    const int ray  = blockIdx.x * 4 + (threadIdx.x >> 6);
    const int px   = ray % HWH;
    const int py   = (ray / HWH) % HWH;
    const int b    = ray / (HWH * HWH);
    const int s    = b >> 2;
    const float focal = focal_p[0];
    const float znear = znear_p[0];
    const float zfar  = zfar_p[0];
    const float* P = tpose + b * 16;
    float ysc = ((py + 0.5f) / (float)HWH) * 2.f - 1.f;
    float xsc = ((px + 0.5f) / (float)HWH) * 2.f - 1.f;
    float dcx = xsc / focal, dcy = -ysc / focal, dcz = -1.f;
    float dirx = P[0]*dcx + P[1]*dcy + P[2]*dcz;
    float diry = P[4]*dcx + P[5]*dcy + P[6]*dcz;
    float dirz = P[8]*dcx + P[9]*dcy + P[10]*dcz;
    float tv  = znear + (zfar - znear) * ((float)lane / (float)(SPR - 1));
    float ptx = P[3] + tv * dirx, pty = P[7] + tv * diry, ptz = P[11] + tv * dirz;
    float feats[NC];
    #pragma unroll
    for (int c = 0; c < NC; c++) feats[c] = 0.f;
    const float minz = focal * znear, maxz = focal * zfar;
    for (int v = 0; v < NVIN; v++) {
        const float* E = ipose + (s * NVIN + v) * 16;
        float qx = ptx - E[3], qy = pty - E[7], qz = ptz - E[11];
        float lx = E[0]*qx + E[4]*qy + E[8]*qz;
        float ly = E[1]*qx + E[5]*qy + E[9]*qz;
        float lz = E[2]*qx + E[6]*qy + E[10]*qz;
        float zz = -lz;
        float u  = lx / zz * focal;
        float vv = ly / zz * focal;
        float wd = 2.f * (zz - minz) / (maxz - minz) - 1.f;
        float ix = ((u   + 1.f) * NW - 1.f) * 0.5f;
        float iy = ((-vv + 1.f) * NH - 1.f) * 0.5f;
        float iz = ((-wd + 1.f) * ND - 1.f) * 0.5f;
        float x0 = floorf(ix), y0 = floorf(iy), z0 = floorf(iz);
        float wgt[8]; int idx[8];
        #pragma unroll
        for (int k = 0; k < 8; k++) {
            float xc = x0 + (k & 1), yc = y0 + ((k >> 1) & 1), zc = z0 + (k >> 2);
            float wt = (1.f - fabsf(ix - xc)) * (1.f - fabsf(iy - yc)) * (1.f - fabsf(iz - zc));
            bool valid = (xc >= 0.f) && (xc < (float)NW) &&
                         (yc >= 0.f) && (yc < (float)NH) &&
                         (zc >= 0.f) && (zc < (float)ND);
            wgt[k] = valid ? wt : 0.f;
            int xi = min(max((int)xc, 0), NW - 1);
            int yi = min(max((int)yc, 0), NH - 1);
            int zi = min(max((int)zc, 0), ND - 1);
            idx[k] = (zi * NH + yi) * NW + xi;
        }
        const float* VB = enc + (size_t)(s * NVIN + v) * NC * DHW;
        #pragma unroll
        for (int c = 0; c < NC; c++) {
            const float* vc = VB + c * DHW;
            float acc = 0.f;
            #pragma unroll
            for (int k = 0; k < 8; k++) acc += wgt[k] * vc[idx[k]];
            feats[c] += acc;
        }
    }
    #pragma unroll
    for (int c = 0; c < NC; c++) feats[c] *= (1.f / 3.f);
    mlp_and_composite(feats, lane, b, py, px, tv, znear, zfar,
                      W1, B1, W2, B2, W3, B3, rhalf);
}

// 2x bilinear upsample, align_corners=True.
__global__ __launch_bounds__(256) void upsample_kernel(
    const float* __restrict__ in, float* __restrict__ out)
{
    int tid = blockIdx.x * 256 + threadIdx.x;
    int ox = tid % NW;
    int oy = (tid / NW) % NH;
    int c  = (tid / (NW * NH)) % NC;
    int b  = tid / (NW * NH * NC);
    const float sc = (float)((HWH - 1) / (double)(NH - 1)); // 47/95
    float pyf = oy * sc;
    float pxf = ox * sc;
    int y0 = (int)floorf(pyf); int y1 = min(y0 + 1, HWH - 1); float fy = pyf - y0;
    int x0 = (int)floorf(pxf); int x1 = min(x0 + 1, HWH - 1); float fx = pxf - x0;
    const float* src = in + (b * NC + c) * HWH * HWH;
    float v00 = src[y0 * HWH + x0], v01 = src[y0 * HWH + x1];
    float v10 = src[y1 * HWH + x0], v11 = src[y1 * HWH + x1];
    float gl = v00 * (1.f - fy) + v10 * fy;
    float gr = v01 * (1.f - fy) + v11 * fy;
    out[tid] = gl * (1.f - fx) + gr * fx;
}

extern "C" void kernel_launch(void* const* d_in, const int* in_sizes, int n_in,
                              void* d_out, int out_size, void* d_ws, size_t ws_size,
                              hipStream_t stream) {
    const float* enc   = (const float*)d_in[0];
    const float* ipose = (const float*)d_in[1];
    const float* tpose = (const float*)d_in[2];
    const float* focal = (const float*)d_in[3];
    const float* znear = (const float*)d_in[4];
    const float* zfar  = (const float*)d_in[5];
    const float* W1 = (const float*)d_in[7];
    const float* B1 = (const float*)d_in[8];
    const float* W2 = (const float*)d_in[9];
    const float* B2 = (const float*)d_in[10];
    const float* W3 = (const float*)d_in[11];
    const float* B3 = (const float*)d_in[12];

    float* out = (float*)d_out;
    const int nrays = NS * NVT * HWH * HWH;              // 18432
    const int nout  = NS * NVT * NC * NH * NW;           // 1179648
    const size_t enc_t_bytes = (size_t)NS * NVIN * NC * DHW * 4;   // 226.5 MB
    const size_t rhalf_bytes = (size_t)nrays * NC * 4;             // 1.18 MB
    const size_t wfrag_bytes = 16 * 64 * 8 * sizeof(short);        // 16 KB
    const size_t xbuf_bytes  = (size_t)NSAMP * NC * 4;             // 75.5 MB

    if (ws_size >= enc_t_bytes + rhalf_bytes + 2 * wfrag_bytes + xbuf_bytes) {
        char* base = (char*)d_ws;
        float* enc_t = (float*)base;                      base += enc_t_bytes;
        float* rhalf = (float*)base;                      base += rhalf_bytes;
        short* whi   = (short*)base;                      base += wfrag_bytes;
        short* wlo   = (short*)base;                      base += wfrag_bytes;
        float* xbuf  = (float*)base;

        wprep_kernel<<<4, 256, 0, stream>>>(W1, W2, W3, whi, wlo);
        transpose_kernel<<<NS * NVIN * NTILE, 256, 0, stream>>>(enc, enc_t);
        gather_kernel<<<NSAMP * 4 / 256, 256, 0, stream>>>(
            enc_t, ipose, tpose, focal, znear, zfar, xbuf);
        mlp_kernel<<<nrays / 4, 256, 0, stream>>>(
            xbuf, znear, zfar, whi, wlo, B1, B2, B3, rhalf);
        upsample_kernel<<<nout / 256, 256, 0, stream>>>(rhalf, out);
    } else {
        float* rhalf = (float*)d_ws;
        render_kernel<<<nrays / 4, 256, 0, stream>>>(
            enc, ipose, tpose, focal, znear, zfar,
            W1, B1, W2, B2, W3, B3, rhalf);
        upsample_kernel<<<nout / 256, 256, 0, stream>>>(rhalf, out);
    }
}